// Round 1
// baseline (1126.963 us; speedup 1.0000x reference)
//
#include <hip/hip_runtime.h>

#define NN 100000
#define EE 1600000
#define DD 128
#define TD 640
#define EPSV 1e-5f

typedef __attribute__((ext_vector_type(8))) short bf16x8;
typedef __attribute__((ext_vector_type(4))) float f32x4;

__device__ inline unsigned short f2b(float f) {
  union { float f; unsigned u; } x; x.f = f;
  unsigned r = x.u + 0x7fff + ((x.u >> 16) & 1);
  return (unsigned short)(r >> 16);
}
__device__ inline float b2f(unsigned short u) {
  union { unsigned u; float f; } x; x.u = ((unsigned)u) << 16;
  return x.f;
}

// ---------- BN stats, stage 1: 256 blocks x 256 thr, partial sum/sumsq per column
__global__ __launch_bounds__(256) void k_stats_partial(const float* __restrict__ x,
    float* __restrict__ ps, float* __restrict__ pq) {
  __shared__ float ls[256], lq[256];
  int t = threadIdx.x;
  int col = t & 127, sub = t >> 7;
  float s = 0.f, q = 0.f;
  for (int r = blockIdx.x * 2 + sub; r < NN; r += 512) {
    float v = x[r * DD + col];
    s += v; q += v * v;
  }
  ls[t] = s; lq[t] = q;
  __syncthreads();
  if (t < 128) {
    ps[blockIdx.x * DD + t] = ls[t] + ls[t + 128];
    pq[blockIdx.x * DD + t] = lq[t] + lq[t + 128];
  }
}

// ---------- BN stats, stage 2: per-column scale/shift
__global__ void k_stats_final(const float* __restrict__ ps, const float* __restrict__ pq,
    const float* __restrict__ g, const float* __restrict__ be, float* __restrict__ ssb) {
  int c = threadIdx.x;  // 128 threads
  float s = 0.f, q = 0.f;
  for (int b = 0; b < 256; ++b) { s += ps[b * DD + c]; q += pq[b * DD + c]; }
  float mean = s * (1.0f / NN);
  float var  = q * (1.0f / NN) - mean * mean;
  float sc = g[c] * rsqrtf(var + EPSV);
  ssb[c] = sc;
  ssb[DD + c] = be[c] - mean * sc;
}

// ---------- fused BN+ReLU+bf16 cast: A[n,d] = bf16(relu(x*scale+shift))
__global__ __launch_bounds__(256) void k_act(const float* __restrict__ x,
    const float* __restrict__ ss, unsigned short* __restrict__ A) {
  int i = blockIdx.x * 256 + threadIdx.x;  // [0, NN*DD/4) exactly
  float4 v = reinterpret_cast<const float4*>(x)[i];
  int c4 = (i & 31) * 4;
  float s0 = ss[c4+0], s1 = ss[c4+1], s2 = ss[c4+2], s3 = ss[c4+3];
  float h0 = ss[DD+c4+0], h1 = ss[DD+c4+1], h2 = ss[DD+c4+2], h3 = ss[DD+c4+3];
  ushort4 o;
  o.x = f2b(fmaxf(0.f, v.x * s0 + h0));
  o.y = f2b(fmaxf(0.f, v.y * s1 + h1));
  o.z = f2b(fmaxf(0.f, v.z * s2 + h2));
  o.w = f2b(fmaxf(0.f, v.w * s3 + h3));
  reinterpret_cast<ushort4*>(A)[i] = o;
}

// ---------- weight fp32 -> bf16
__global__ void k_cvt(const float* __restrict__ w, unsigned short* __restrict__ o) {
  int i = blockIdx.x * 256 + threadIdx.x;  // [0, 640*128/4) exactly
  float4 v = reinterpret_cast<const float4*>(w)[i];
  ushort4 u; u.x = f2b(v.x); u.y = f2b(v.y); u.z = f2b(v.z); u.w = f2b(v.w);
  reinterpret_cast<ushort4*>(o)[i] = u;
}

// ---------- CSR build
__global__ void k_zero(int* p, int n) {
  int i = blockIdx.x * 256 + threadIdx.x;
  if (i < n) p[i] = 0;
}
__global__ void k_hist(const int* __restrict__ dst, int* __restrict__ cnt) {
  int i = blockIdx.x * 256 + threadIdx.x;
  if (i < EE) atomicAdd(&cnt[dst[i]], 1);
}
__global__ __launch_bounds__(1024) void k_scan(const int* cnt, int* row_ptr, int* cursor) {
  __shared__ int sh[1024];
  int t = threadIdx.x;
  int running = 0;
  for (int base = 0; base < NN; base += 1024) {
    int idx = base + t;
    int v = (idx < NN) ? cnt[idx] : 0;
    sh[t] = v;
    __syncthreads();
    for (int off = 1; off < 1024; off <<= 1) {
      int add = (t >= off) ? sh[t - off] : 0;
      __syncthreads();
      sh[t] += add;
      __syncthreads();
    }
    int excl = sh[t] - v;
    if (idx < NN) { row_ptr[idx] = running + excl; cursor[idx] = running + excl; }
    int total = sh[1023];
    __syncthreads();
    running += total;
  }
  if (t == 0) row_ptr[NN] = running;
}
__global__ void k_scatter(const int* __restrict__ src, const int* __restrict__ dst,
    const int* __restrict__ et, int* __restrict__ cursor, int* __restrict__ payload) {
  int i = blockIdx.x * 256 + threadIdx.x;
  if (i < EE) {
    int pos = atomicAdd(&cursor[dst[i]], 1);
    payload[pos] = (src[i] << 3) | et[i];
  }
}

// ---------- bf16 MFMA GEMM: H[N,640] = A[N,128] * W^T + bias, stored bf16
__global__ __launch_bounds__(256) void k_gemm(const unsigned short* __restrict__ A,
    const unsigned short* __restrict__ W, const float* __restrict__ bias,
    unsigned short* __restrict__ H) {
  const int l = threadIdx.x & 63;
  const int w = threadIdx.x >> 6;
  const int R = blockIdx.x * 64 + w * 16;  // 16 rows per wave
  const int C = blockIdx.y * 64;
  const int lm = l & 15;
  const int lk = (l >> 4) * 8;
  int arow = R + lm; if (arow >= NN) arow = NN - 1;
  const unsigned short* aptr = A + arow * DD + lk;
  f32x4 acc[4] = {};
#pragma unroll
  for (int kk = 0; kk < 4; ++kk) {
    bf16x8 af = *reinterpret_cast<const bf16x8*>(aptr + kk * 32);
#pragma unroll
    for (int f = 0; f < 4; ++f) {
      const unsigned short* bptr = W + (C + f * 16 + lm) * DD + kk * 32 + lk;
      bf16x8 bfr = *reinterpret_cast<const bf16x8*>(bptr);
      acc[f] = __builtin_amdgcn_mfma_f32_16x16x32_bf16(af, bfr, acc[f], 0, 0, 0);
    }
  }
  const int r0 = R + (l >> 4) * 4;
#pragma unroll
  for (int f = 0; f < 4; ++f) {
    int col = C + f * 16 + lm;
    float bv = bias[col];
#pragma unroll
    for (int r = 0; r < 4; ++r) {
      int row = r0 + r;
      if (row < NN) H[row * TD + col] = f2b(acc[f][r] + bv);
    }
  }
}

// ---------- per-dst segment sum of gathered type-slices
__global__ __launch_bounds__(128) void k_gather(const unsigned short* __restrict__ H,
    const int* __restrict__ rp, const int* __restrict__ pl,
    const float* __restrict__ base, float* __restrict__ y) {
  int m = blockIdx.x;
  int d = threadIdx.x;
  int s = rp[m], e = rp[m + 1];
  float acc = base ? base[m * DD + d] : 0.f;
  for (int j = s; j < e; ++j) {
    int p = pl[j];
    acc += b2f(H[(p >> 3) * TD + (p & 7) * DD + d]);
  }
  y[m * DD + d] = acc;
}

extern "C" void kernel_launch(void* const* d_in, const int* in_sizes, int n_in,
                              void* d_out, int out_size, void* d_ws, size_t ws_size,
                              hipStream_t stream) {
  const float* features = (const float*)d_in[0];
  const int*   src   = (const int*)d_in[1];
  const int*   dst   = (const int*)d_in[2];
  const int*   etype = (const int*)d_in[3];
  const float* w1  = (const float*)d_in[4];
  const float* b1  = (const float*)d_in[5];
  const float* g1  = (const float*)d_in[6];
  const float* be1 = (const float*)d_in[7];
  const float* w2  = (const float*)d_in[8];
  const float* b2  = (const float*)d_in[9];
  const float* g2  = (const float*)d_in[10];
  const float* be2 = (const float*)d_in[11];

  char* ws = (char*)d_ws;
  unsigned short* Ab   = (unsigned short*)(ws + 0);            // 25,600,000 B
  unsigned short* Hb   = (unsigned short*)(ws + 25600000);     // 128,000,000 B
  float*          y1   = (float*)(ws + 153600000);             // 51,200,000 B
  unsigned short* w1b  = (unsigned short*)(ws + 204800000);    // 163,840 B
  unsigned short* w2b  = (unsigned short*)(ws + 204963840);    // 163,840 B
  float*          ssb  = (float*)(ws + 205127680);             // 1,024 B
  float*          ps   = (float*)(ws + 205128704);             // 131,072 B
  float*          pq   = (float*)(ws + 205259776);             // 131,072 B
  int*            rowp = (int*)(ws + 205390848);               // 400,016 B
  int*            curs = (int*)(ws + 205790864);               // 400,000 B
  int*            payl = (int*)(ws + 206190864);               // 6,400,000 B
  // total: 212,590,864 B

  // CSR build (shared by both rounds)
  k_zero<<<(NN + 255) / 256, 256, 0, stream>>>(curs, NN);
  k_hist<<<(EE + 255) / 256, 256, 0, stream>>>(dst, curs);
  k_scan<<<1, 1024, 0, stream>>>(curs, rowp, curs);
  k_scatter<<<(EE + 255) / 256, 256, 0, stream>>>(src, dst, etype, curs, payl);

  // weights -> bf16
  k_cvt<<<80, 256, 0, stream>>>(w1, w1b);
  k_cvt<<<80, 256, 0, stream>>>(w2, w2b);

  dim3 gemm_grid(1563, 10);

  // ---- round 1
  k_stats_partial<<<256, 256, 0, stream>>>(features, ps, pq);
  k_stats_final<<<1, 128, 0, stream>>>(ps, pq, g1, be1, ssb);
  k_act<<<12500, 256, 0, stream>>>(features, ssb, Ab);
  k_gemm<<<gemm_grid, 256, 0, stream>>>(Ab, w1b, b1, Hb);
  k_gather<<<NN, 128, 0, stream>>>(Hb, rowp, payl, nullptr, y1);

  // ---- round 2
  k_stats_partial<<<256, 256, 0, stream>>>(y1, ps, pq);
  k_stats_final<<<1, 128, 0, stream>>>(ps, pq, g2, be2, ssb);
  k_act<<<12500, 256, 0, stream>>>(y1, ssb, Ab);
  k_gemm<<<gemm_grid, 256, 0, stream>>>(Ab, w2b, b2, Hb);
  k_gather<<<NN, 128, 0, stream>>>(Hb, rowp, payl, features, (float*)d_out);
}

// Round 2
// 617.604 us; speedup vs baseline: 1.8247x; 1.8247x over previous
//
#include <hip/hip_runtime.h>

#define NN 100000
#define EE 1600000
#define DD 128
#define TD 640
#define EPSV 1e-5f
#define NBLK_SCAN 391   // ceil(NN/256)

typedef __attribute__((ext_vector_type(8))) short bf16x8;
typedef __attribute__((ext_vector_type(4))) float f32x4;

__device__ inline unsigned short f2b(float f) {
  union { float f; unsigned u; } x; x.f = f;
  unsigned r = x.u + 0x7fff + ((x.u >> 16) & 1);
  return (unsigned short)(r >> 16);
}
__device__ inline float b2f(unsigned short u) {
  union { unsigned u; float f; } x; x.u = ((unsigned)u) << 16;
  return x.f;
}

// ---------- BN stats, stage 1
__global__ __launch_bounds__(256) void k_stats_partial(const float* __restrict__ x,
    float* __restrict__ ps, float* __restrict__ pq) {
  __shared__ float ls[256], lq[256];
  int t = threadIdx.x;
  int col = t & 127, sub = t >> 7;
  float s = 0.f, q = 0.f;
  for (int r = blockIdx.x * 2 + sub; r < NN; r += 512) {
    float v = x[r * DD + col];
    s += v; q += v * v;
  }
  ls[t] = s; lq[t] = q;
  __syncthreads();
  if (t < 128) {
    ps[blockIdx.x * DD + t] = ls[t] + ls[t + 128];
    pq[blockIdx.x * DD + t] = lq[t] + lq[t + 128];
  }
}

// ---------- BN stats, stage 2
__global__ void k_stats_final(const float* __restrict__ ps, const float* __restrict__ pq,
    const float* __restrict__ g, const float* __restrict__ be, float* __restrict__ ssb) {
  int c = threadIdx.x;  // 128 threads
  float s = 0.f, q = 0.f;
  for (int b = 0; b < 256; ++b) { s += ps[b * DD + c]; q += pq[b * DD + c]; }
  float mean = s * (1.0f / NN);
  float var  = q * (1.0f / NN) - mean * mean;
  float sc = g[c] * rsqrtf(var + EPSV);
  ssb[c] = sc;
  ssb[DD + c] = be[c] - mean * sc;
}

// ---------- fused BN+ReLU+bf16 cast
__global__ __launch_bounds__(256) void k_act(const float* __restrict__ x,
    const float* __restrict__ ss, unsigned short* __restrict__ A) {
  int i = blockIdx.x * 256 + threadIdx.x;  // [0, NN*DD/4) exactly
  float4 v = reinterpret_cast<const float4*>(x)[i];
  int c4 = (i & 31) * 4;
  float s0 = ss[c4+0], s1 = ss[c4+1], s2 = ss[c4+2], s3 = ss[c4+3];
  float h0 = ss[DD+c4+0], h1 = ss[DD+c4+1], h2 = ss[DD+c4+2], h3 = ss[DD+c4+3];
  ushort4 o;
  o.x = f2b(fmaxf(0.f, v.x * s0 + h0));
  o.y = f2b(fmaxf(0.f, v.y * s1 + h1));
  o.z = f2b(fmaxf(0.f, v.z * s2 + h2));
  o.w = f2b(fmaxf(0.f, v.w * s3 + h3));
  reinterpret_cast<ushort4*>(A)[i] = o;
}

// ---------- weight fp32 -> bf16
__global__ void k_cvt(const float* __restrict__ w, unsigned short* __restrict__ o) {
  int i = blockIdx.x * 256 + threadIdx.x;  // [0, 640*128/4) exactly
  float4 v = reinterpret_cast<const float4*>(w)[i];
  ushort4 u; u.x = f2b(v.x); u.y = f2b(v.y); u.z = f2b(v.z); u.w = f2b(v.w);
  reinterpret_cast<ushort4*>(o)[i] = u;
}

// ---------- CSR build
__global__ void k_zero(int* p, int n) {
  int i = blockIdx.x * 256 + threadIdx.x;
  if (i < n) p[i] = 0;
}
__global__ void k_hist(const int* __restrict__ dst, int* __restrict__ cnt) {
  int i = blockIdx.x * 256 + threadIdx.x;
  if (i < EE) atomicAdd(&cnt[dst[i]], 1);
}
// 3-phase scan: per-block totals -> scan totals -> per-block rescan + offset
__global__ __launch_bounds__(256) void k_scan_blk(const int* __restrict__ cnt, int* __restrict__ bsum) {
  __shared__ int sh[256];
  int idx = blockIdx.x * 256 + threadIdx.x;
  sh[threadIdx.x] = (idx < NN) ? cnt[idx] : 0;
  __syncthreads();
  for (int off = 128; off > 0; off >>= 1) {
    if (threadIdx.x < off) sh[threadIdx.x] += sh[threadIdx.x + off];
    __syncthreads();
  }
  if (threadIdx.x == 0) bsum[blockIdx.x] = sh[0];
}
__global__ __launch_bounds__(512) void k_scan_top(int* __restrict__ bsum) {
  __shared__ int sh[512];
  int t = threadIdx.x;
  int v = (t < NBLK_SCAN) ? bsum[t] : 0;
  sh[t] = v;
  __syncthreads();
  for (int off = 1; off < 512; off <<= 1) {
    int add = (t >= off) ? sh[t - off] : 0;
    __syncthreads();
    sh[t] += add;
    __syncthreads();
  }
  if (t < NBLK_SCAN) bsum[t] = sh[t] - v;  // exclusive
}
__global__ __launch_bounds__(256) void k_scan_fin(const int* __restrict__ cnt,
    const int* __restrict__ bsum, int* __restrict__ row_ptr, int* __restrict__ cursor) {
  __shared__ int sh[256];
  int idx = blockIdx.x * 256 + threadIdx.x;
  int v = (idx < NN) ? cnt[idx] : 0;
  sh[threadIdx.x] = v;
  __syncthreads();
  for (int off = 1; off < 256; off <<= 1) {
    int add = (threadIdx.x >= off) ? sh[threadIdx.x - off] : 0;
    __syncthreads();
    sh[threadIdx.x] += add;
    __syncthreads();
  }
  int excl = bsum[blockIdx.x] + sh[threadIdx.x] - v;
  if (idx < NN) { row_ptr[idx] = excl; cursor[idx] = excl; }
  if (idx == NN - 1) row_ptr[NN] = excl + v;
}
__global__ void k_scatter(const int* __restrict__ src, const int* __restrict__ dst,
    const int* __restrict__ et, int* __restrict__ cursor, int* __restrict__ payload) {
  int i = blockIdx.x * 256 + threadIdx.x;
  if (i < EE) {
    int pos = atomicAdd(&cursor[dst[i]], 1);
    payload[pos] = (src[i] << 3) | et[i];
  }
}

// ---------- bf16 MFMA GEMM: H[N,640] = A[N,128] * W^T + bias, stored bf16
// B fragments held in registers per wave; grid-stride over row tiles.
__global__ __launch_bounds__(256) void k_gemm(const unsigned short* __restrict__ A,
    const unsigned short* __restrict__ W, const float* __restrict__ bias,
    unsigned short* __restrict__ H) {
  const int l = threadIdx.x & 63;
  const int w = threadIdx.x >> 6;
  const int C = blockIdx.y * 64;
  const int lm = l & 15;
  const int lk = (l >> 4) * 8;

  // load B fragments once: 4 kk x 4 f
  bf16x8 bfr[4][4];
#pragma unroll
  for (int kk = 0; kk < 4; ++kk)
#pragma unroll
    for (int f = 0; f < 4; ++f)
      bfr[kk][f] = *reinterpret_cast<const bf16x8*>(W + (C + f * 16 + lm) * DD + kk * 32 + lk);

  float bv[4];
#pragma unroll
  for (int f = 0; f < 4; ++f) bv[f] = bias[C + f * 16 + lm];

  const int NT = 1563;  // ceil(NN/64)
  for (int tile = blockIdx.x; tile < NT; tile += gridDim.x) {
    const int R = tile * 64 + w * 16;
    int arow = R + lm; if (arow >= NN) arow = NN - 1;
    const unsigned short* aptr = A + arow * DD + lk;
    f32x4 acc[4] = {};
#pragma unroll
    for (int kk = 0; kk < 4; ++kk) {
      bf16x8 af = *reinterpret_cast<const bf16x8*>(aptr + kk * 32);
#pragma unroll
      for (int f = 0; f < 4; ++f)
        acc[f] = __builtin_amdgcn_mfma_f32_16x16x32_bf16(af, bfr[kk][f], acc[f], 0, 0, 0);
    }
    const int r0 = R + (l >> 4) * 4;
#pragma unroll
    for (int f = 0; f < 4; ++f) {
      int col = C + f * 16 + lm;
#pragma unroll
      for (int r = 0; r < 4; ++r) {
        int row = r0 + r;
        if (row < NN) H[row * TD + col] = f2b(acc[f][r] + bv[f]);
      }
    }
  }
}

// ---------- per-dst segment sum, 1 wave per node, ushort2 per lane
__global__ __launch_bounds__(64) void k_gather(const unsigned short* __restrict__ H,
    const int* __restrict__ rp, const int* __restrict__ pl,
    const float* __restrict__ base, float* __restrict__ y) {
  int m = blockIdx.x;
  int l = threadIdx.x;  // 0..63
  int s = rp[m], e = rp[m + 1];
  float a0 = 0.f, a1 = 0.f;
  if (base) {
    float2 b = reinterpret_cast<const float2*>(base)[m * 64 + l];
    a0 = b.x; a1 = b.y;
  }
  int j = s;
  for (; j + 1 < e; j += 2) {
    int p0 = pl[j], p1 = pl[j + 1];
    ushort2 u0 = reinterpret_cast<const ushort2*>(H + (p0 >> 3) * TD + (p0 & 7) * DD)[l];
    ushort2 u1 = reinterpret_cast<const ushort2*>(H + (p1 >> 3) * TD + (p1 & 7) * DD)[l];
    a0 += b2f(u0.x) + b2f(u1.x);
    a1 += b2f(u0.y) + b2f(u1.y);
  }
  if (j < e) {
    int p0 = pl[j];
    ushort2 u0 = reinterpret_cast<const ushort2*>(H + (p0 >> 3) * TD + (p0 & 7) * DD)[l];
    a0 += b2f(u0.x);
    a1 += b2f(u0.y);
  }
  float2 o; o.x = a0; o.y = a1;
  reinterpret_cast<float2*>(y)[m * 64 + l] = o;
}

extern "C" void kernel_launch(void* const* d_in, const int* in_sizes, int n_in,
                              void* d_out, int out_size, void* d_ws, size_t ws_size,
                              hipStream_t stream) {
  const float* features = (const float*)d_in[0];
  const int*   src   = (const int*)d_in[1];
  const int*   dst   = (const int*)d_in[2];
  const int*   etype = (const int*)d_in[3];
  const float* w1  = (const float*)d_in[4];
  const float* b1  = (const float*)d_in[5];
  const float* g1  = (const float*)d_in[6];
  const float* be1 = (const float*)d_in[7];
  const float* w2  = (const float*)d_in[8];
  const float* b2  = (const float*)d_in[9];
  const float* g2  = (const float*)d_in[10];
  const float* be2 = (const float*)d_in[11];

  char* ws = (char*)d_ws;
  unsigned short* Ab   = (unsigned short*)(ws + 0);            // 25,600,000 B
  unsigned short* Hb   = (unsigned short*)(ws + 25600000);     // 128,000,000 B
  float*          y1   = (float*)(ws + 153600000);             // 51,200,000 B
  unsigned short* w1b  = (unsigned short*)(ws + 204800000);    // 163,840 B
  unsigned short* w2b  = (unsigned short*)(ws + 204963840);    // 163,840 B
  float*          ssb  = (float*)(ws + 205127680);             // 1,024 B
  float*          ps   = (float*)(ws + 205128704);             // 131,072 B
  float*          pq   = (float*)(ws + 205259776);             // 131,072 B
  int*            rowp = (int*)(ws + 205390848);               // 400,016 B
  int*            curs = (int*)(ws + 205790864);               // 400,000 B
  int*            payl = (int*)(ws + 206190864);               // 6,400,000 B
  int*            bsum = (int*)(ws + 212590864);               // 2,048 B
  // total: 212,592,912 B

  // CSR build (shared by both rounds)
  k_zero<<<(NN + 255) / 256, 256, 0, stream>>>(curs, NN);
  k_hist<<<(EE + 255) / 256, 256, 0, stream>>>(dst, curs);
  k_scan_blk<<<NBLK_SCAN, 256, 0, stream>>>(curs, bsum);
  k_scan_top<<<1, 512, 0, stream>>>(bsum);
  k_scan_fin<<<NBLK_SCAN, 256, 0, stream>>>(curs, bsum, rowp, curs);
  k_scatter<<<(EE + 255) / 256, 256, 0, stream>>>(src, dst, etype, curs, payl);

  // weights -> bf16
  k_cvt<<<80, 256, 0, stream>>>(w1, w1b);
  k_cvt<<<80, 256, 0, stream>>>(w2, w2b);

  dim3 gemm_grid(391, 10);

  // ---- round 1
  k_stats_partial<<<256, 256, 0, stream>>>(features, ps, pq);
  k_stats_final<<<1, 128, 0, stream>>>(ps, pq, g1, be1, ssb);
  k_act<<<12500, 256, 0, stream>>>(features, ssb, Ab);
  k_gemm<<<gemm_grid, 256, 0, stream>>>(Ab, w1b, b1, Hb);
  k_gather<<<NN, 64, 0, stream>>>(Hb, rowp, payl, nullptr, y1);

  // ---- round 2
  k_stats_partial<<<256, 256, 0, stream>>>(y1, ps, pq);
  k_stats_final<<<1, 128, 0, stream>>>(ps, pq, g2, be2, ssb);
  k_act<<<12500, 256, 0, stream>>>(y1, ssb, Ab);
  k_gemm<<<gemm_grid, 256, 0, stream>>>(Ab, w2b, b2, Hb);
  k_gather<<<NN, 64, 0, stream>>>(Hb, rowp, payl, features, (float*)d_out);
}